// Round 6
// baseline (334.553 us; speedup 1.0000x reference)
//
#include <hip/hip_runtime.h>

// TokenMixer: out[n,b,c] = x_pos[n,b,c] * (1 - sigmoid(cos_sim(x_pre[n,b,:], x_pos[n,b,:])))
// N=4096, B=16, C=512 -> 65536 rows of 512 fp32.
//
// V6: two-pass clean-stream split (diagnostic + candidate win).
//   Evidence: V1/V3/V4b/V5 (4 schedules, incl. FORCED 8KB/wave in flight and
//   stream time-skew) all ~110-117us @ 2.44 TB/s HBM with traffic at floor
//   (134MB fetch + 131MB write). MLP/skew theories dead; the fused kernel's
//   3-stream hit/miss-interleaved pattern is served at 2.44 TB/s, period.
//   Probe: split into (1) read-mostly reduce pass producing w[row] (256 KB
//   workspace), which also re-fills L3 with the full 256 MiB of inputs, and
//   (2) a copy-shaped scale pass (read pos [L3-hot] + w, write out).
//   rocprof reports each pass separately -> decisive on "pattern effect vs
//   environmental plateau" regardless of outcome.

typedef float f32x4 __attribute__((ext_vector_type(4)));

constexpr int C_DIM = 512;
constexpr int ROWS  = 4096 * 16;   // 65536

// ---- Pass 1: one wave per row -> w[row] = 1 - sigmoid(cos_sim) ----
__global__ __launch_bounds__(256) void weights_kernel(
    const float* __restrict__ pre,
    const float* __restrict__ pos,
    float* __restrict__ w)
{
    const int row  = (int)((blockIdx.x * 256u + threadIdx.x) >> 6);
    const int lane = (int)(threadIdx.x & 63u);
    const size_t base = (size_t)row * C_DIM + (size_t)(lane * 8);

    const f32x4 p0 = *(const f32x4*)(pre + base);
    const f32x4 p1 = *(const f32x4*)(pre + base + 4);
    const f32x4 q0 = *(const f32x4*)(pos + base);
    const f32x4 q1 = *(const f32x4*)(pos + base + 4);

    float sp = 0.f, sq = 0.f, d = 0.f;
#pragma unroll
    for (int i = 0; i < 4; ++i) {
        sp = fmaf(p0[i], p0[i], sp); sp = fmaf(p1[i], p1[i], sp);
        sq = fmaf(q0[i], q0[i], sq); sq = fmaf(q1[i], q1[i], sq);
        d  = fmaf(p0[i], q0[i], d);  d  = fmaf(p1[i], q1[i], d);
    }
#pragma unroll
    for (int m = 1; m < 64; m <<= 1) {
        sp += __shfl_xor(sp, m, 64);
        sq += __shfl_xor(sq, m, 64);
        d  += __shfl_xor(d,  m, 64);
    }
    if (lane == 0) {
        const float np = fmaxf(sqrtf(sp), 1e-12f);
        const float nq = fmaxf(sqrtf(sq), 1e-12f);
        // 1 - sigmoid(x) = 1 / (1 + e^x)
        w[row] = 1.0f / (1.0f + __expf(d / (np * nq)));
    }
}

// ---- Pass 2: copy-shaped scale: out[row,:] = pos[row,:] * w[row] ----
__global__ __launch_bounds__(256) void scale_kernel(
    const float* __restrict__ pos,
    const float* __restrict__ w,
    float* __restrict__ out)
{
    const int row  = (int)((blockIdx.x * 256u + threadIdx.x) >> 6);
    const int lane = (int)(threadIdx.x & 63u);
    const size_t base = (size_t)row * C_DIM + (size_t)(lane * 8);

    const f32x4 q0 = *(const f32x4*)(pos + base);
    const f32x4 q1 = *(const f32x4*)(pos + base + 4);
    const float wv = w[row];   // wave-uniform, single line, broadcast

    *(f32x4*)(out + base)     = q0 * wv;
    *(f32x4*)(out + base + 4) = q1 * wv;
}

// ---- Fallback (workspace too small): V1 fused, known-good 110us ----
__global__ __launch_bounds__(256) void fused_kernel(
    const float* __restrict__ pre,
    const float* __restrict__ pos,
    float* __restrict__ out)
{
    const int row  = (int)((blockIdx.x * 256u + threadIdx.x) >> 6);
    const int lane = (int)(threadIdx.x & 63u);
    const size_t base = (size_t)row * C_DIM + (size_t)(lane * 8);

    const f32x4 p0 = *(const f32x4*)(pre + base);
    const f32x4 p1 = *(const f32x4*)(pre + base + 4);
    const f32x4 q0 = *(const f32x4*)(pos + base);
    const f32x4 q1 = *(const f32x4*)(pos + base + 4);

    float sp = 0.f, sq = 0.f, d = 0.f;
#pragma unroll
    for (int i = 0; i < 4; ++i) {
        sp = fmaf(p0[i], p0[i], sp); sp = fmaf(p1[i], p1[i], sp);
        sq = fmaf(q0[i], q0[i], sq); sq = fmaf(q1[i], q1[i], sq);
        d  = fmaf(p0[i], q0[i], d);  d  = fmaf(p1[i], q1[i], d);
    }
#pragma unroll
    for (int m = 1; m < 64; m <<= 1) {
        sp += __shfl_xor(sp, m, 64);
        sq += __shfl_xor(sq, m, 64);
        d  += __shfl_xor(d,  m, 64);
    }
    const float np = fmaxf(sqrtf(sp), 1e-12f);
    const float nq = fmaxf(sqrtf(sq), 1e-12f);
    const float wv = 1.0f / (1.0f + __expf(d / (np * nq)));

    *(f32x4*)(out + base)     = q0 * wv;
    *(f32x4*)(out + base + 4) = q1 * wv;
}

extern "C" void kernel_launch(void* const* d_in, const int* in_sizes, int n_in,
                              void* d_out, int out_size, void* d_ws, size_t ws_size,
                              hipStream_t stream) {
    const float* pre = (const float*)d_in[0];
    const float* pos = (const float*)d_in[1];
    float* out = (float*)d_out;

    const int blocks = ROWS / 4;   // wave per row, 4 waves/block -> 16384

    if (ws_size >= (size_t)ROWS * sizeof(float)) {
        float* w = (float*)d_ws;
        weights_kernel<<<blocks, 256, 0, stream>>>(pre, pos, w);
        scale_kernel<<<blocks, 256, 0, stream>>>(pos, w, out);
    } else {
        fused_kernel<<<blocks, 256, 0, stream>>>(pre, pos, out);
    }
}